// Round 6
// baseline (570.039 us; speedup 1.0000x reference)
//
#include <hip/hip_runtime.h>

#define D_ 300
#define C_ 10
#define I_ 6
#define NPOS 16384
#define NROWS 27              // 1 u + 10 cin + 10 cout + 6 info
#define NDOT 70
#define ROWF 304              // floats per row slot (1216 B, 16B-aligned)
#define BUFPAD 212            // tail-garbage spill pad after last row (floats)
#define BUFF (NROWS * ROWF + BUFPAD)   // 8420 floats per buffer
#define WPB 2                 // waves per block
#define PPW 32                // positions per wave
#define NBLK (NPOS / (WPB * PPW))      // 256 blocks
#define NPART (NBLK * WPB)             // 512 partials

__device__ __forceinline__ float neg_log_sigmoid(float x) {
    return __logf(1.0f + __expf(-x));   // x in [-10,10], fp32-safe
}
__device__ __forceinline__ float dot4(float4 a, float4 b) {
    return a.x * b.x + a.y * b.y + a.z * b.z + a.w * b.w;
}
__device__ __forceinline__ void dma16(const float* g, float* l) {
    // async global->LDS DMA, 16B/lane; LDS dest = uniform base + lane*16
    __builtin_amdgcn_global_load_lds(
        (const __attribute__((address_space(1))) void*)g,
        (__attribute__((address_space(3))) void*)l, 16, 0, 0);
}

__global__ __launch_bounds__(128) void hg2vec_pos_kernel(
    const int* __restrict__ pos_u, const int* __restrict__ pos_v,
    const int* __restrict__ info_v,
    const float* __restrict__ W_in, const float* __restrict__ W_out,
    const float* __restrict__ context_mask, const float* __restrict__ sig_mask,
    const float* __restrict__ score_mask, float* __restrict__ partial)
{
    // uniform wave id (readfirstlane -> divergence analysis sees uniform,
    // so index loads become s_load (lgkmcnt), keeping vmcnt DMA-only)
    const int wv = __builtin_amdgcn_readfirstlane((int)(threadIdx.x >> 6));
    const int lane = threadIdx.x & 63;
    const int p0 = (blockIdx.x * WPB + wv) * PPW;

    __shared__ float s_buf[WPB][2][BUFF];     // 134.7 KB
    __shared__ float s_red[WPB][8][71];       // 4.5 KB

    // per-lane epilogue constants (fixed dot assignment across positions)
    const int d1 = lane;                // 0..63 < 70
    const int c1 = d1 / 7, t1 = d1 - 7 * c1;
    float m1_cm = 0, m1_sm = 0, m1_scm = 0;
    if (t1 == 0) m1_cm = context_mask[c1];
    else { m1_sm = sig_mask[t1 - 1]; m1_scm = score_mask[t1 - 1]; }
    const int d2 = 64 + lane;
    const bool has2 = d2 < NDOT;        // lanes 0..5
    const int c2 = d2 / 7, t2 = d2 - 7 * c2;
    float m2_sm = 0, m2_scm = 0;        // t2 is always >0 for d2 in 64..69
    if (has2) { m2_sm = sig_mask[t2 - 1]; m2_scm = score_mask[t2 - 1]; }

    const int lc = (lane < 11) ? lane : 10;      // clamped tail lane
    const float zf = (lane < 11) ? 1.0f : 0.0f;

    int su, scv[C_], siv[I_];
    auto load_idx = [&](int p) {
        su = pos_u[p];
#pragma unroll
        for (int c = 0; c < C_; ++c) scv[c] = pos_v[p * C_ + c];
#pragma unroll
        for (int i = 0; i < I_; ++i) siv[i] = info_v[p * I_ + i];
    };
    auto row_g = [&](int r) -> const float* {
        if (r == 0)  return W_out + (size_t)su * D_;
        if (r <= 10) return W_in  + (size_t)scv[r - 1] * D_;
        if (r <= 20) return W_out + (size_t)scv[r - 11] * D_;
        return W_in + (size_t)siv[r - 21] * D_;
    };
    auto fill = [&](int bi) {
        float* base = &s_buf[wv][bi][0];
        // tails first: any exec-sloppy overlap garbage is overwritten by the
        // (younger, in-order-retiring) full-part DMAs below
#pragma unroll
        for (int r = 0; r < NROWS; ++r) {
            const float* g = row_g(r);
            if (lane < 11) dma16(g + 256 + 4 * lc, base + r * ROWF + 256);
        }
#pragma unroll
        for (int r = 0; r < NROWS; ++r)
            dma16(row_g(r) + 4 * lane, base + r * ROWF);
    };

    float acc = 0.0f;

    load_idx(p0);
    fill(0);

    for (int j = 0; j < PPW; ++j) {
        if (j < PPW - 1) {
            load_idx(p0 + j + 1);          // s_load, lgkm only
            fill((j + 1) & 1);             // 54 async DMAs
            asm volatile("s_waitcnt vmcnt(54)" ::: "memory");  // fill(p) done
        } else {
            asm volatile("s_waitcnt vmcnt(0)" ::: "memory");
        }

        const float* base = &s_buf[wv][j & 1][0];
        const int o0 = 4 * lane;
        const int o1 = 256 + 4 * lc;

        // resident rows: u (row 0), info (rows 21..26); tails zeroed
        float4 u0 = *(const float4*)(base + 0 * ROWF + o0);
        float4 u1 = *(const float4*)(base + 0 * ROWF + o1);
        u1.x *= zf; u1.y *= zf; u1.z *= zf; u1.w *= zf;
        float4 in0[I_], in1[I_];
#pragma unroll
        for (int i = 0; i < I_; ++i) {
            const float* r = base + (21 + i) * ROWF;
            in0[i] = *(const float4*)(r + o0);
            float4 t = *(const float4*)(r + o1);
            t.x *= zf; t.y *= zf; t.z *= zf; t.w *= zf;
            in1[i] = t;
        }

        const int g = lane >> 3;
        const bool writer = (lane & 7) == 0;
#pragma unroll
        for (int c = 0; c < C_; ++c) {
            const float* ra = base + (1 + c) * ROWF;       // ctx_in
            const float* rb = base + (11 + c) * ROWF;      // ctx_out
            const float4 a0 = *(const float4*)(ra + o0);
            const float4 a1 = *(const float4*)(ra + o1);   // tail*u1==0
            const float4 b0 = *(const float4*)(rb + o0);
            const float4 b1 = *(const float4*)(rb + o1);   // tail*in1==0
            float part[7];
            part[0] = dot4(u0, a0) + dot4(u1, a1);
#pragma unroll
            for (int i = 0; i < I_; ++i)
                part[1 + i] = dot4(b0, in0[i]) + dot4(b1, in1[i]);
#pragma unroll
            for (int t = 0; t < 7; ++t) {
                float v = part[t];
                v += __shfl_xor(v, 1, 64);
                v += __shfl_xor(v, 2, 64);
                v += __shfl_xor(v, 4, 64);
                if (writer) s_red[wv][g][c * 7 + t] = v;
            }
        }

        // epilogue: each lane finalizes its fixed dot(s)
        {
            float s = s_red[wv][0][d1] + s_red[wv][1][d1] + s_red[wv][2][d1]
                    + s_red[wv][3][d1] + s_red[wv][4][d1] + s_red[wv][5][d1]
                    + s_red[wv][6][d1] + s_red[wv][7][d1];
            if (t1 == 0) {
                float x = s * m1_cm;
                x = fminf(fmaxf(x, -10.0f), 10.0f);
                acc += neg_log_sigmoid(x);
            } else {
                float x = fminf(fmaxf(s, -10.0f), 10.0f) * m1_sm;
                acc += neg_log_sigmoid(x) * m1_scm;
            }
            if (has2) {
                float s2 = s_red[wv][0][d2] + s_red[wv][1][d2] + s_red[wv][2][d2]
                         + s_red[wv][3][d2] + s_red[wv][4][d2] + s_red[wv][5][d2]
                         + s_red[wv][6][d2] + s_red[wv][7][d2];
                float x = fminf(fmaxf(s2, -10.0f), 10.0f) * m2_sm;
                acc += neg_log_sigmoid(x) * m2_scm;
            }
        }
    }

#pragma unroll
    for (int off = 32; off; off >>= 1) acc += __shfl_xor(acc, off, 64);
    if (lane == 0) partial[blockIdx.x * WPB + wv] = acc;
}

// 512 partials -> out[0]; 128 threads, one float4 each
__global__ __launch_bounds__(128) void hg2vec_reduce_kernel(
    const float* __restrict__ partial, float* __restrict__ out)
{
    float4 v = ((const float4*)partial)[threadIdx.x];
    float a = (v.x + v.y) + (v.z + v.w);
#pragma unroll
    for (int off = 32; off; off >>= 1) a += __shfl_xor(a, off, 64);
    __shared__ float s[2];
    if ((threadIdx.x & 63) == 0) s[threadIdx.x >> 6] = a;
    __syncthreads();
    if (threadIdx.x == 0) out[0] = s[0] + s[1];
}

extern "C" void kernel_launch(void* const* d_in, const int* in_sizes, int n_in,
                              void* d_out, int out_size, void* d_ws, size_t ws_size,
                              hipStream_t stream) {
    const int* pos_u = (const int*)d_in[0];
    const int* pos_v = (const int*)d_in[1];
    const int* info_v = (const int*)d_in[2];
    const float* W_in = (const float*)d_in[3];
    const float* W_out = (const float*)d_in[4];
    const float* context_mask = (const float*)d_in[5];
    const float* sig_mask = (const float*)d_in[6];
    const float* score_mask = (const float*)d_in[7];
    float* out = (float*)d_out;
    float* partial = (float*)d_ws;   // NPART floats = 2 KB scratch

    hg2vec_pos_kernel<<<NBLK, 128, 0, stream>>>(
        pos_u, pos_v, info_v, W_in, W_out,
        context_mask, sig_mask, score_mask, partial);
    hg2vec_reduce_kernel<<<1, 128, 0, stream>>>(partial, out);
}